// Round 2
// baseline (20727.376 us; speedup 1.0000x reference)
//
#include <hip/hip_runtime.h>
#include <math.h>

// Seq2SeqGRU persistent kernel. B=256, T=512, H=512, OUT=10.
// 256 WGs x 384 threads (6 waves). WG = (rowgroup rg of 16 batch rows, 2 hid slices).
// waves 0-1: layer0 (enc) / dec0;  2-3: layer1 gi;  4-5: layer1 gh (+LN/fc duties).
// Weights live in registers (192 VGPR/wave). Cross-WG sync: per-rg device-scope flags.
// blockIdx = hp*16+rg  => all 16 WGs of rg on XCD rg%8 (round-robin heuristic).

#define Hdim 512
#define Bsz  256
#define Tlen 512
#define OUTL 10

typedef _Float16 half8 __attribute__((ext_vector_type(8)));
typedef float    f32x4 __attribute__((ext_vector_type(4)));

__device__ __forceinline__ f32x4 mfma16(half8 a, half8 b, f32x4 c) {
    return __builtin_amdgcn_mfma_f32_16x16x32_f16(a, b, c, 0, 0, 0);
}
__device__ __forceinline__ float sigf(float v) { return 1.0f / (1.0f + __expf(-v)); }

__device__ __forceinline__ void wait_ge(int* f, int target) {
    if (target <= 0) return;
    while (__hip_atomic_load(f, __ATOMIC_RELAXED, __HIP_MEMORY_SCOPE_AGENT) < target)
        __builtin_amdgcn_s_sleep(1);
    __builtin_amdgcn_fence(__ATOMIC_ACQUIRE, "agent");
}
__device__ __forceinline__ void signal(int* f) {
    if ((threadIdx.x & 63) == 0)
        __hip_atomic_fetch_add(f, 1, __ATOMIC_RELEASE, __HIP_MEMORY_SCOPE_AGENT);
}
__device__ __forceinline__ half8 ld_cvt(const float* p) {
    float4 a = *(const float4*)p;
    float4 b = *(const float4*)(p + 4);
    half8 v;
    v[0]=(_Float16)a.x; v[1]=(_Float16)a.y; v[2]=(_Float16)a.z; v[3]=(_Float16)a.w;
    v[4]=(_Float16)b.x; v[5]=(_Float16)b.y; v[6]=(_Float16)b.z; v[7]=(_Float16)b.w;
    return v;
}

// LayerNorm of 16 rows (one wave). In-place on f32, also writes f16 copy.
__device__ void ln_rows(float* hT, _Float16* dst16, const float* gam, const float* bet,
                        int row0, int lane) {
    #pragma unroll 1
    for (int r = 0; r < 16; ++r) {
        float* p = hT + (size_t)(row0 + r) * Hdim;
        float4 v0 = *(const float4*)(p + lane * 8);
        float4 v1 = *(const float4*)(p + lane * 8 + 4);
        float s  = v0.x + v0.y + v0.z + v0.w + v1.x + v1.y + v1.z + v1.w;
        float sq = v0.x*v0.x + v0.y*v0.y + v0.z*v0.z + v0.w*v0.w
                 + v1.x*v1.x + v1.y*v1.y + v1.z*v1.z + v1.w*v1.w;
        #pragma unroll
        for (int m = 1; m < 64; m <<= 1) { s += __shfl_xor(s, m); sq += __shfl_xor(sq, m); }
        float mean = s * (1.0f / Hdim);
        float rstd = rsqrtf(sq * (1.0f / Hdim) - mean * mean + 1e-5f);
        float vv[8] = {v0.x, v0.y, v0.z, v0.w, v1.x, v1.y, v1.z, v1.w};
        _Float16* d = dst16 + (size_t)(row0 + r) * Hdim;
        #pragma unroll
        for (int e = 0; e < 8; ++e) {
            int k = lane * 8 + e;
            float o = (vv[e] - mean) * rstd * gam[k] + bet[k];
            p[k] = o;
            d[k] = (_Float16)o;
        }
    }
}

__global__ __launch_bounds__(384, 2) void gru_all(
    const float* __restrict__ x,
    const float* __restrict__ ewih0, const float* __restrict__ ewhh0,
    const float* __restrict__ ebih0, const float* __restrict__ ebhh0,
    const float* __restrict__ ewih1, const float* __restrict__ ewhh1,
    const float* __restrict__ ebih1, const float* __restrict__ ebhh1,
    const float* __restrict__ lng,   const float* __restrict__ lnb,
    const float* __restrict__ dwih0, const float* __restrict__ dwhh0,
    const float* __restrict__ dbih0, const float* __restrict__ dbhh0,
    const float* __restrict__ dwih1, const float* __restrict__ dwhh1,
    const float* __restrict__ dbih1, const float* __restrict__ dbhh1,
    const float* __restrict__ fcw,   const float* __restrict__ fcb,
    float* __restrict__ out,
    _Float16* h0a, _Float16* h0b, _Float16* h1a, _Float16* h1b,
    float* hT0, float* hT1, float* ybuf, int* flags)
{
    __shared__ _Float16 ldsA[16][520];      // h0/y0 tile, rows padded to 1040B
    __shared__ _Float16 ldsB[16][520];      // h1 tile
    __shared__ float    ldsAcc[2][3][256];  // gi->gh handoff [pair][gate][row*16+col]

    const int tid  = threadIdx.x;
    const int wid  = tid >> 6, lane = tid & 63;
    const int role = wid >> 1;              // 0=L0/dec0, 1=GI, 2=GH
    const int pr   = wid & 1;               // which of the WG's two hid slices
    const int rg   = blockIdx.x & 15, hp = blockIdx.x >> 4;
    const int cv   = lane & 15, kg = lane >> 4;
    const int hs   = hp * 2 + pr;
    const int hid  = hs * 16 + cv;
    const int row0 = rg * 16;
    const int rb   = kg * 4;

    int* f0  = flags + (0 * 16 + rg) * 16;
    int* f1  = flags + (1 * 16 + rg) * 16;
    int* fLN = flags + (2 * 16 + rg) * 16;
    int* fD0 = flags + (3 * 16 + rg) * 16;
    int* fD1 = flags + (4 * 16 + rg) * 16;
    int* fY  = flags + (5 * 16 + rg) * 16;

    _Float16* h0buf[2] = {h0a, h0b};
    _Float16* h1buf[2] = {h1a, h1b};

    // ---- encoder weights -> registers (B-frag: lane cv = weight row(hid), kg*8 = k chunk)
    half8 w0[16], w1[16], w2[16];
    {
        const float* wsP = role == 0 ? ewhh0 : (role == 1 ? ewih1 : ewhh1);
        const float* b0 = wsP + (size_t)hid * Hdim + kg * 8;
        #pragma unroll
        for (int kk = 0; kk < 16; ++kk) {
            w0[kk] = ld_cvt(b0 + kk * 32);
            w1[kk] = ld_cvt(b0 + (size_t)512 * Hdim + kk * 32);
            w2[kk] = ld_cvt(b0 + (size_t)1024 * Hdim + kk * 32);
        }
    }
    float cw_r0 = 0, cw_r1 = 0, cw_z0 = 0, cw_z1 = 0, cw_n0 = 0, cw_n1 = 0;
    float bCr = 0, bCz = 0, bIn = 0, bHn = 0;
    if (role == 0) {
        cw_r0 = ewih0[hid * 2];          cw_r1 = ewih0[hid * 2 + 1];
        cw_z0 = ewih0[(512 + hid) * 2];  cw_z1 = ewih0[(512 + hid) * 2 + 1];
        cw_n0 = ewih0[(1024 + hid) * 2]; cw_n1 = ewih0[(1024 + hid) * 2 + 1];
        bCr = ebih0[hid] + ebhh0[hid];
        bCz = ebih0[512 + hid] + ebhh0[512 + hid];
        bIn = ebih0[1024 + hid]; bHn = ebhh0[1024 + hid];
    } else if (role == 2) {
        bCr = ebih1[hid] + ebhh1[hid];
        bCz = ebih1[512 + hid] + ebhh1[512 + hid];
        bIn = ebih1[1024 + hid]; bHn = ebhh1[1024 + hid];
    }
    float hold[4] = {0.f, 0.f, 0.f, 0.f};   // per-lane fp32 h carry (own (b,hid) cells)

#define STAGE_TILES(S0, S1)                                                    \
    do {                                                                       \
        for (int c = tid; c < 2048; c += 384) {                                \
            int r_ = (c >> 6) & 15, cc_ = c & 63;                              \
            if (c < 1024) *(half8*)&ldsA[r_][cc_ * 8] =                        \
                *(const half8*)((S0) + r_ * Hdim + cc_ * 8);                   \
            else          *(half8*)&ldsB[r_][cc_ * 8] =                        \
                *(const half8*)((S1) + r_ * Hdim + cc_ * 8);                   \
        }                                                                      \
    } while (0)

    // ================= encoder: 513 iterations =================
    // iter i: layer0 step i (i<512), layer1 step i-1 (i>=1)
    for (int i = 0; i <= Tlen; ++i) {
        wait_ge(f0, 32 * i);            // h0[i-1] complete
        wait_ge(f1, 32 * (i - 1));      // h1[i-2] complete
        {
            const _Float16* s0 = h0buf[(i - 1) & 1] + (size_t)row0 * Hdim;
            const _Float16* s1 = h1buf[(i - 2) & 1] + (size_t)row0 * Hdim;
            STAGE_TILES(s0, s1);
        }
        __syncthreads();   // B: stage visible
        f32x4 a0 = {0,0,0,0}, a1 = {0,0,0,0}, a2 = {0,0,0,0};
        if (role == 2) {
            if (i >= 1) {
                #pragma unroll
                for (int kk = 0; kk < 16; ++kk) {
                    half8 a = *(const half8*)&ldsB[cv][kk * 32 + kg * 8];
                    a0 = mfma16(a, w0[kk], a0);
                    a1 = mfma16(a, w1[kk], a1);
                    a2 = mfma16(a, w2[kk], a2);
                }
            }
        } else if (role == 0) {
            if (i < Tlen) {
                #pragma unroll
                for (int kk = 0; kk < 16; ++kk) {
                    half8 a = *(const half8*)&ldsA[cv][kk * 32 + kg * 8];
                    a0 = mfma16(a, w0[kk], a0);
                    a1 = mfma16(a, w1[kk], a1);
                    a2 = mfma16(a, w2[kk], a2);
                }
                _Float16* dst = h0buf[i & 1];
                #pragma unroll
                for (int jj = 0; jj < 4; ++jj) {
                    int b = row0 + rb + jj;
                    const float* xp = x + ((size_t)b * Tlen + i) * 2;
                    float x0 = xp[0], x1 = xp[1];
                    float r = sigf(x0 * cw_r0 + x1 * cw_r1 + a0[jj] + bCr);
                    float z = sigf(x0 * cw_z0 + x1 * cw_z1 + a1[jj] + bCz);
                    float n = tanhf(x0 * cw_n0 + x1 * cw_n1 + bIn + r * (a2[jj] + bHn));
                    float hv = (1.0f - z) * n + z * hold[jj];
                    hold[jj] = hv;
                    dst[(size_t)b * Hdim + hid] = (_Float16)hv;
                    if (i == Tlen - 1) hT0[(size_t)b * Hdim + hid] = hv;
                }
                signal(f0);
            }
        } else { // GI: gi = y0[i-1] @ wih1^T
            if (i >= 1) {
                #pragma unroll
                for (int kk = 0; kk < 16; ++kk) {
                    half8 a = *(const half8*)&ldsA[cv][kk * 32 + kg * 8];
                    a0 = mfma16(a, w0[kk], a0);
                    a1 = mfma16(a, w1[kk], a1);
                    a2 = mfma16(a, w2[kk], a2);
                }
                #pragma unroll
                for (int jj = 0; jj < 4; ++jj) {
                    int rr = (rb + jj) * 16 + cv;
                    ldsAcc[pr][0][rr] = a0[jj];
                    ldsAcc[pr][1][rr] = a1[jj];
                    ldsAcc[pr][2][rr] = a2[jj];
                }
            }
        }
        __syncthreads();   // C: ldsAcc visible
        if (role == 2 && i >= 1) {
            _Float16* dst = h1buf[(i - 1) & 1];
            #pragma unroll
            for (int jj = 0; jj < 4; ++jj) {
                int b = row0 + rb + jj;
                int rr = (rb + jj) * 16 + cv;
                float gr = ldsAcc[pr][0][rr];
                float gz = ldsAcc[pr][1][rr];
                float gn = ldsAcc[pr][2][rr];
                float r = sigf(gr + a0[jj] + bCr);
                float z = sigf(gz + a1[jj] + bCz);
                float n = tanhf(gn + bIn + r * (a2[jj] + bHn));
                float hv = (1.0f - z) * n + z * hold[jj];
                hold[jj] = hv;
                dst[(size_t)b * Hdim + hid] = (_Float16)hv;
                if (i == Tlen) hT1[(size_t)b * Hdim + hid] = hv;
            }
            signal(f1);
        }
    }

    // ================= LayerNorm phase =================
    if (hp == 0 && wid == 0) {
        wait_ge(f0, 32 * Tlen);
        wait_ge(f1, 32 * Tlen);           // ensure all consumers of h0[511] done
        ln_rows(hT0, h0buf[1], lng, lnb, row0, lane);
        if (lane < 16) {
            int b = row0 + lane;
            ybuf[b] = x[((size_t)b * Tlen + (Tlen - 1)) * 2 + 1];
        }
        signal(fLN);
    }
    if (hp == 0 && wid == 4) {
        wait_ge(f1, 32 * Tlen);
        ln_rows(hT1, h1buf[1], lng, lnb, row0, lane);
        signal(fLN);
    }

    // ---- decoder weights -> registers ----
    {
        const float* wsP = role == 0 ? dwhh0 : (role == 1 ? dwih1 : dwhh1);
        const float* b0 = wsP + (size_t)hid * Hdim + kg * 8;
        #pragma unroll
        for (int kk = 0; kk < 16; ++kk) {
            w0[kk] = ld_cvt(b0 + kk * 32);
            w1[kk] = ld_cvt(b0 + (size_t)512 * Hdim + kk * 32);
            w2[kk] = ld_cvt(b0 + (size_t)1024 * Hdim + kk * 32);
        }
    }
    if (role == 0) {
        cw_r0 = dwih0[hid]; cw_z0 = dwih0[512 + hid]; cw_n0 = dwih0[1024 + hid];
        bCr = dbih0[hid] + dbhh0[hid];
        bCz = dbih0[512 + hid] + dbhh0[512 + hid];
        bIn = dbih0[1024 + hid]; bHn = dbhh0[1024 + hid];
    } else if (role == 2) {
        bCr = dbih1[hid] + dbhh1[hid];
        bCz = dbih1[512 + hid] + dbhh1[512 + hid];
        bIn = dbih1[1024 + hid]; bHn = dbhh1[1024 + hid];
    }
    float fw[8] = {0,0,0,0,0,0,0,0};
    float fb = 0.f;
    const bool is_fc = (hp == 0 && wid == 4);
    if (is_fc) {
        #pragma unroll
        for (int e = 0; e < 8; ++e) fw[e] = fcw[lane * 8 + e];
        fb = fcb[0];
    }
    wait_ge(fLN, 2);
    if (role == 0) {
        #pragma unroll
        for (int jj = 0; jj < 4; ++jj)
            hold[jj] = hT0[(size_t)(row0 + rb + jj) * Hdim + hid];
    } else if (role == 2) {
        #pragma unroll
        for (int jj = 0; jj < 4; ++jj)
            hold[jj] = hT1[(size_t)(row0 + rb + jj) * Hdim + hid];
    }

    // ================= decoder: 10 full steps =================
    for (int t = 0; t < OUTL; ++t) {
        wait_ge(fD0, 32 * t);
        wait_ge(fD1, 32 * t);
        if (role == 0) wait_ge(fY, t);
        {
            const _Float16* s0 = h0buf[(t - 1) & 1] + (size_t)row0 * Hdim;
            const _Float16* s1 = h1buf[(t - 1) & 1] + (size_t)row0 * Hdim;
            STAGE_TILES(s0, s1);
        }
        __syncthreads();
        f32x4 a0 = {0,0,0,0}, a1 = {0,0,0,0}, a2 = {0,0,0,0};
        if (role == 0) {
            #pragma unroll
            for (int kk = 0; kk < 16; ++kk) {
                half8 a = *(const half8*)&ldsA[cv][kk * 32 + kg * 8];
                a0 = mfma16(a, w0[kk], a0);
                a1 = mfma16(a, w1[kk], a1);
                a2 = mfma16(a, w2[kk], a2);
            }
            _Float16* dst = h0buf[t & 1];
            #pragma unroll
            for (int jj = 0; jj < 4; ++jj) {
                int b = row0 + rb + jj;
                float yv = ybuf[b];
                float r = sigf(yv * cw_r0 + a0[jj] + bCr);
                float z = sigf(yv * cw_z0 + a1[jj] + bCz);
                float n = tanhf(yv * cw_n0 + bIn + r * (a2[jj] + bHn));
                float hv = (1.0f - z) * n + z * hold[jj];
                hold[jj] = hv;
                dst[(size_t)b * Hdim + hid] = (_Float16)hv;
            }
            signal(fD0);
        } else if (role == 1) {
            wait_ge(fD0, 32 * (t + 1));   // h0dec[t] fresh from global
            const _Float16* ag = h0buf[t & 1] + (size_t)(row0 + cv) * Hdim + kg * 8;
            #pragma unroll
            for (int kk = 0; kk < 16; ++kk) {
                half8 a = *(const half8*)(ag + kk * 32);
                a0 = mfma16(a, w0[kk], a0);
                a1 = mfma16(a, w1[kk], a1);
                a2 = mfma16(a, w2[kk], a2);
            }
            #pragma unroll
            for (int jj = 0; jj < 4; ++jj) {
                int rr = (rb + jj) * 16 + cv;
                ldsAcc[pr][0][rr] = a0[jj];
                ldsAcc[pr][1][rr] = a1[jj];
                ldsAcc[pr][2][rr] = a2[jj];
            }
        } else {
            #pragma unroll
            for (int kk = 0; kk < 16; ++kk) {
                half8 a = *(const half8*)&ldsB[cv][kk * 32 + kg * 8];
                a0 = mfma16(a, w0[kk], a0);
                a1 = mfma16(a, w1[kk], a1);
                a2 = mfma16(a, w2[kk], a2);
            }
        }
        __syncthreads();
        if (role == 2) {
            _Float16* dst = h1buf[t & 1];
            #pragma unroll
            for (int jj = 0; jj < 4; ++jj) {
                int b = row0 + rb + jj;
                int rr = (rb + jj) * 16 + cv;
                float gr = ldsAcc[pr][0][rr];
                float gz = ldsAcc[pr][1][rr];
                float gn = ldsAcc[pr][2][rr];
                float r = sigf(gr + a0[jj] + bCr);
                float z = sigf(gz + a1[jj] + bCz);
                float n = tanhf(gn + bIn + r * (a2[jj] + bHn));
                float hv = (1.0f - z) * n + z * hold[jj];
                hold[jj] = hv;
                dst[(size_t)b * Hdim + hid] = (_Float16)hv;
            }
            signal(fD1);
            if (is_fc) {
                wait_ge(fD1, 32 * (t + 1));
                const _Float16* hsrc = h1buf[t & 1];
                #pragma unroll 1
                for (int r2 = 0; r2 < 16; ++r2) {
                    int b = row0 + r2;
                    half8 hv8 = *(const half8*)(hsrc + (size_t)b * Hdim + lane * 8);
                    float pa = 0.f;
                    #pragma unroll
                    for (int e = 0; e < 8; ++e) pa += (float)hv8[e] * fw[e];
                    #pragma unroll
                    for (int m = 1; m < 64; m <<= 1) pa += __shfl_xor(pa, m);
                    if (lane == 0) {
                        float yv2 = pa + fb;
                        ybuf[b] = yv2;
                        out[(size_t)b * OUTL + t] = yv2;
                    }
                }
                signal(fY);
            }
        }
    }
#undef STAGE_TILES
}

extern "C" void kernel_launch(void* const* d_in, const int* in_sizes, int n_in,
                              void* d_out, int out_size, void* d_ws, size_t ws_size,
                              hipStream_t stream)
{
    const float* x     = (const float*)d_in[0];
    const float* ewih0 = (const float*)d_in[1];
    const float* ewhh0 = (const float*)d_in[2];
    const float* ebih0 = (const float*)d_in[3];
    const float* ebhh0 = (const float*)d_in[4];
    const float* ewih1 = (const float*)d_in[5];
    const float* ewhh1 = (const float*)d_in[6];
    const float* ebih1 = (const float*)d_in[7];
    const float* ebhh1 = (const float*)d_in[8];
    const float* lng   = (const float*)d_in[9];
    const float* lnb   = (const float*)d_in[10];
    const float* dwih0 = (const float*)d_in[11];
    const float* dwhh0 = (const float*)d_in[12];
    const float* dbih0 = (const float*)d_in[13];
    const float* dbhh0 = (const float*)d_in[14];
    const float* dwih1 = (const float*)d_in[15];
    const float* dwhh1 = (const float*)d_in[16];
    const float* dbih1 = (const float*)d_in[17];
    const float* dbhh1 = (const float*)d_in[18];
    const float* fcw   = (const float*)d_in[19];
    const float* fcb   = (const float*)d_in[20];
    float* out = (float*)d_out;
    (void)in_sizes; (void)n_in; (void)out_size; (void)ws_size;

    char* ws = (char*)d_ws;
    size_t off = 0;
    auto alloc = [&](size_t bytes) -> void* {
        void* p = ws + off;
        off += (bytes + 255) & ~(size_t)255;
        return p;
    };

    // Layout: [flags][h0a][h0b][h1a][h1b] (all zeroed each call) [hT0][hT1][ybuf]
    int* flags = (int*)alloc(6 * 16 * 16 * sizeof(int));          // 6KB
    const size_t HB = (size_t)Bsz * Hdim;
    _Float16* h0a = (_Float16*)alloc(HB * 2);
    _Float16* h0b = (_Float16*)alloc(HB * 2);
    _Float16* h1a = (_Float16*)alloc(HB * 2);
    _Float16* h1b = (_Float16*)alloc(HB * 2);
    size_t zbytes = off;                                          // ~1.03MB
    float* hT0  = (float*)alloc(HB * 4);
    float* hT1  = (float*)alloc(HB * 4);
    float* ybuf = (float*)alloc(Bsz * 4);

    hipMemsetAsync(d_ws, 0, zbytes, stream);

    gru_all<<<256, 384, 0, stream>>>(
        x, ewih0, ewhh0, ebih0, ebhh0, ewih1, ewhh1, ebih1, ebhh1,
        lng, lnb, dwih0, dwhh0, dbih0, dbhh0, dwih1, dwhh1, dbih1, dbhh1,
        fcw, fcb, out, h0a, h0b, h1a, h1b, hT0, hT1, ybuf, flags);
}